// Round 10
// baseline (1408.622 us; speedup 1.0000x reference)
//
#include <hip/hip_runtime.h>

#define DEV __device__ __forceinline__

typedef __bf16 bf16x8 __attribute__((ext_vector_type(8)));
typedef float  f32x4  __attribute__((ext_vector_type(4)));

DEV float b2f(unsigned short u) {
    unsigned int t = ((unsigned int)u) << 16;
    return __uint_as_float(t);
}
DEV unsigned short f2b(float f) {
    unsigned int u = __float_as_uint(f);
    unsigned int r = (u + 0x7FFFu + ((u >> 16) & 1u)) >> 16;
    return (unsigned short)r;
}

DEV void gload_lds16(const unsigned short* g, void* l) {
    __builtin_amdgcn_global_load_lds(
        (const __attribute__((address_space(1))) void*)(const void*)g,
        (__attribute__((address_space(3))) void*)l, 16, 0, 0);
}

// dest window-row -> source/dest token index (roll by SS=3, window 7x7, 56x56, 64 win/batch)
DEV size_t win_to_tok(int row) {
    int w = row / 49, t = row - w * 49;
    int b  = w >> 6, widx = w & 63;
    int wi = widx >> 3, wj = widx & 7;
    int ti = t / 7, tj = t - ti * 7;
    int hh = wi * 7 + ti + 3; if (hh >= 56) hh -= 56;
    int ww = wj * 7 + tj + 3; if (ww >= 56) ww -= 56;
    return (size_t)b * 3136 + (size_t)hh * 56 + ww;
}

// ---------------- weight prep: fp32 [K][N] -> bf16 [N][K] ----------------
__global__ void wprep(const float* __restrict__ src, unsigned short* __restrict__ dst,
                      int K, int N) {
    int idx = blockIdx.x * 256 + threadIdx.x;
    if (idx >= K * N) return;
    int k = idx / N, n = idx - k * N;
    dst[(size_t)n * K + k] = f2b(src[idx]);
}

// ---------------- LayerNorm (+optional shifted-window gather), fp32 -> bf16 ----------------
template <int REMAP>
__global__ __launch_bounds__(256) void ln_kernel(const float* __restrict__ x,
                                                 const float* __restrict__ g,
                                                 const float* __restrict__ b,
                                                 unsigned short* __restrict__ out,
                                                 int rows) {
    int r = blockIdx.x * 4 + (threadIdx.x >> 6);
    int lane = threadIdx.x & 63;
    if (r >= rows) return;
    size_t src = REMAP ? win_to_tok(r) : (size_t)r;
    const float* xp = x + src * 384;
    float v[6];
    float s = 0.f;
#pragma unroll
    for (int i = 0; i < 6; ++i) { v[i] = xp[i * 64 + lane]; s += v[i]; }
#pragma unroll
    for (int off = 32; off; off >>= 1) s += __shfl_xor(s, off, 64);
    float mu = s * (1.f / 384.f);
    float q = 0.f;
#pragma unroll
    for (int i = 0; i < 6; ++i) { float d = v[i] - mu; q += d * d; }
#pragma unroll
    for (int off = 32; off; off >>= 1) q += __shfl_xor(q, off, 64);
    float inv = rsqrtf(q * (1.f / 384.f) + 1e-5f);
    unsigned short* op = out + (size_t)r * 384;
#pragma unroll
    for (int i = 0; i < 6; ++i) {
        int c = i * 64 + lane;
        op[c] = f2b((v[i] - mu) * inv * g[c] + b[c]);
    }
}

// ---------------- GEMM: C[M][N] = A[M][K] (bf16, row-major) x Bt[N][K] (bf16) ----------------
// B-panel-stationary, barrier-free K-loop:
//  - per 192-k chunk: stage B [128 cols][192 k] (48 KB) to LDS once (12 gload_lds issues,
//    one vmcnt(0)+barrier); XOR-swizzled (phys c16 = kc ^ ((row>>1)&3)), pre-swizzled source.
//  - inner 6 steps (32 k each), fully unrolled, ZERO barriers: 4 A-frags global->VGPR
//    (depth-1 register double-buffer), 4 ds_read_b128 of B (2-way bank = free), 16 MFMA.
//  128x128 tile, 4 waves (2x2), 3 blocks/CU (48 KB LDS, ~140 VGPR).
// MODE 0: out bf16 = C                               (QKV)
// MODE 1: h[tok] = x[tok] + C + bias  (un-window+un-roll remap, fp32 out)   (proj)
// MODE 2: out bf16 = gelu(C + bias)   (tanh-form)    (FFN1)
// MODE 3: outf = resid + C + bias  (resid may alias outf)                   (FFN2)
template <int MODE>
__global__ __launch_bounds__(256, 3) void gemm_kernel(const unsigned short* __restrict__ A,
                                                      const unsigned short* __restrict__ Bt,
                                                      int M, int N, int K,
                                                      const float* __restrict__ bias,
                                                      const float* __restrict__ resid,
                                                      unsigned short* __restrict__ outb,
                                                      float* __restrict__ outf) {
    __shared__ unsigned short Blds[6 * 128 * 32];   // 48 KB: [kblk 0..5][row 0..127][32 elems]
    const int tid = threadIdx.x;
    const int wid = tid >> 6, lane = tid & 63;
    const int ntile = N >> 7;

    // XCD-aware block swizzle (grid % 8 == 0 for all launches)
    int bid = blockIdx.x;
    int nwg = gridDim.x;
    int swb = ((nwg & 7) == 0) ? ((bid & 7) * (nwg >> 3) + (bid >> 3)) : bid;
    const int mt = swb / ntile, nt = swb - mt * ntile;
    const int wr = wid >> 1, wc = wid & 1;
    const int fr = lane & 15, kq = lane >> 4;

    f32x4 acc[4][4] = {};

    // B staging: thread t, issue j: row r=(j&1)*64 + (t>>2), kblk=j>>1, linear LDS dest
    // j*4096 + t*16; physical c16 slot (t&3) must hold logical chunk (t&3)^((t>>3)&3).
    const int sc = (tid & 3) ^ ((tid >> 3) & 3);
    const unsigned short* Bg = Bt + (size_t)(nt * 128) * K;

    // A fragment base: row = mt*128 + wr*64 + m*16 + fr, k-offset kq*8 (+m via pointer)
    const unsigned short* Ag = A + (size_t)(mt * 128 + wr * 64 + fr) * K + kq * 8;

    // B read base (bytes): addr = s*8192 + n*1024 + bbase
    const int bbase = (wc * 64 + fr) * 64 + ((kq ^ ((fr >> 1) & 3)) * 16);
    const char* Bb = (const char*)Blds;

    const int KC = K / 192;
    for (int kc = 0; kc < KC; ++kc) {
        if (kc) __syncthreads();                 // all waves done reading previous panel
#pragma unroll
        for (int j = 0; j < 12; ++j) {
            int r = (j & 1) * 64 + (tid >> 2);
            gload_lds16(Bg + (size_t)r * K + kc * 192 + (j >> 1) * 32 + sc * 8,
                        (char*)Blds + j * 4096 + tid * 16);
        }
        asm volatile("s_waitcnt vmcnt(0)" ::: "memory");
        __syncthreads();                         // panel resident for every wave

        const unsigned short* a0 = Ag + kc * 192;
        bf16x8 aC[4], bC[4];
#pragma unroll
        for (int m = 0; m < 4; ++m) aC[m] = *(const bf16x8*)(a0 + (size_t)m * 16 * K);
#pragma unroll
        for (int n = 0; n < 4; ++n) bC[n] = *(const bf16x8*)(Bb + bbase + n * 1024);

#pragma unroll
        for (int s = 0; s < 6; ++s) {
            bf16x8 aN[4], bN[4];
            if (s < 5) {
#pragma unroll
                for (int m = 0; m < 4; ++m)
                    aN[m] = *(const bf16x8*)(a0 + (size_t)m * 16 * K + (s + 1) * 32);
#pragma unroll
                for (int n = 0; n < 4; ++n)
                    bN[n] = *(const bf16x8*)(Bb + bbase + (s + 1) * 8192 + n * 1024);
            }
#pragma unroll
            for (int m = 0; m < 4; ++m)
#pragma unroll
                for (int n = 0; n < 4; ++n)
                    acc[m][n] = __builtin_amdgcn_mfma_f32_16x16x32_bf16(aC[m], bC[n], acc[m][n], 0, 0, 0);
            if (s < 5) {
#pragma unroll
                for (int m = 0; m < 4; ++m) aC[m] = aN[m];
#pragma unroll
                for (int n = 0; n < 4; ++n) bC[n] = bN[n];
            }
        }
    }

    const int row0 = mt * 128 + wr * 64;
    const int col0 = nt * 128 + wc * 64;
#pragma unroll
    for (int m = 0; m < 4; ++m) {
#pragma unroll
        for (int r = 0; r < 4; ++r) {
            int row = row0 + m * 16 + kq * 4 + r;
            size_t tok = 0;
            if constexpr (MODE == 1) tok = win_to_tok(row);
#pragma unroll
            for (int n = 0; n < 4; ++n) {
                int col = col0 + n * 16 + fr;
                float v = acc[m][n][r];
                if constexpr (MODE == 0) {
                    outb[(size_t)row * N + col] = f2b(v);
                } else if constexpr (MODE == 1) {
                    size_t o = tok * 384 + col;
                    outf[o] = resid[o] + v + bias[col];
                } else if constexpr (MODE == 2) {
                    // tanh-form GELU, overflow-safe (err ~3e-4, << bf16 rounding of F)
                    float t2 = v + bias[col];
                    float y  = 0.7978845608028654f * (t2 + 0.044715f * t2 * t2 * t2);
                    float u  = __expf(-2.0f * fabsf(y));
                    float th = (1.f - u) / (1.f + u);
                    outb[(size_t)row * N + col] = f2b(0.5f * t2 * (1.f + copysignf(th, t2)));
                } else {
                    size_t o = (size_t)row * N + col;
                    outf[o] = resid[o] + v + bias[col];
                }
            }
        }
    }
}

// ---------------- attention: one wave per (window, head) ----------------
__global__ __launch_bounds__(64) void attn_kernel(const unsigned short* __restrict__ QKV,
                                                  const int* __restrict__ rel_idx,
                                                  const float* __restrict__ rpb,
                                                  unsigned short* __restrict__ O) {
    __shared__ float Ks[49 * 32];
    __shared__ float Vs[49 * 32];
    int w = blockIdx.x / 12, hd = blockIdx.x - w * 12;
    int lane = threadIdx.x;
    const size_t base = (size_t)w * 49 * 1152;

    for (int i = lane; i < 1568; i += 64) {
        int m = i >> 5, d = i & 31;
        Ks[i] = b2f(QKV[base + (size_t)m * 1152 + 384 + hd * 32 + d]);
        Vs[i] = b2f(QKV[base + (size_t)m * 1152 + 768 + hd * 32 + d]);
    }
    __syncthreads();

    int n = lane < 49 ? lane : 48;
    float q[32];
#pragma unroll
    for (int d = 0; d < 32; ++d)
        q[d] = b2f(QKV[base + (size_t)n * 1152 + hd * 32 + d]) * 0.17677669529663687f;

    int widx = w & 63;
    int wi = widx >> 3, wj = widx & 7;
    auto regionOf = [](int c) { return c < 49 ? 0 : (c < 53 ? 1 : 2); };
    int ti = n / 7, tj = n - (n / 7) * 7;
    int labq = regionOf(wi * 7 + ti) * 3 + regionOf(wj * 7 + tj);

    float sc[49];
    float mx = -1e30f;
#pragma unroll
    for (int m = 0; m < 49; ++m) {
        float s = 0.f;
#pragma unroll
        for (int d = 0; d < 32; ++d) s += q[d] * Ks[m * 32 + d];
        s += rpb[rel_idx[n * 49 + m] * 12 + hd];
        int mi = m / 7, mj = m - (m / 7) * 7;
        int labk = regionOf(wi * 7 + mi) * 3 + regionOf(wj * 7 + mj);
        if (labk != labq) s -= 100.f;
        sc[m] = s;
        mx = fmaxf(mx, s);
    }
    float sum = 0.f;
#pragma unroll
    for (int m = 0; m < 49; ++m) { float e = __expf(sc[m] - mx); sc[m] = e; sum += e; }
    float rinv = 1.f / sum;
    float o[32] = {};
#pragma unroll
    for (int m = 0; m < 49; ++m) {
        float p = sc[m] * rinv;
#pragma unroll
        for (int d = 0; d < 32; ++d) o[d] += p * Vs[m * 32 + d];
    }
    if (lane < 49) {
        unsigned short* op = O + ((size_t)w * 49 + n) * 384 + hd * 32;
#pragma unroll
        for (int d = 0; d < 32; ++d) op[d] = f2b(o[d]);
    }
}

extern "C" void kernel_launch(void* const* d_in, const int* in_sizes, int n_in,
                              void* d_out, int out_size, void* d_ws, size_t ws_size,
                              hipStream_t stream) {
    const float* x     = (const float*)d_in[0];
    const int*   rel   = (const int*)  d_in[3];
    const float* rpb   = (const float*)d_in[4];
    const float* qkvw  = (const float*)d_in[5];
    const float* projw = (const float*)d_in[6];
    const float* projb = (const float*)d_in[7];
    const float* n1g   = (const float*)d_in[8];
    const float* n1b   = (const float*)d_in[9];
    const float* n2g   = (const float*)d_in[10];
    const float* n2b   = (const float*)d_in[11];
    const float* w1    = (const float*)d_in[12];
    const float* b1    = (const float*)d_in[13];
    const float* w2    = (const float*)d_in[14];
    const float* b2    = (const float*)d_in[15];
    float* out = (float*)d_out;

    const int T = in_sizes[0] / 384;   // 100352

    char* ws = (char*)d_ws;
    size_t off = 0;
    auto alloc = [&](size_t bytes) {
        char* p = ws + off;
        off += (bytes + 255) & ~(size_t)255;
        return p;
    };
    unsigned short* WqT = (unsigned short*)alloc((size_t)1152 * 384 * 2);
    unsigned short* WpT = (unsigned short*)alloc((size_t)384 * 384 * 2);
    unsigned short* W1T = (unsigned short*)alloc((size_t)1536 * 384 * 2);
    unsigned short* W2T = (unsigned short*)alloc((size_t)384 * 1536 * 2);
    unsigned short* slotA = (unsigned short*)alloc((size_t)T * 384 * 2);   // X1 -> O -> X2
    unsigned short* slotB = (unsigned short*)alloc((size_t)T * 1536 * 2);  // QKV -> F

    unsigned short* X1  = slotA;
    unsigned short* O   = slotA;
    unsigned short* X2  = slotA;
    unsigned short* QKV = slotB;
    unsigned short* F   = slotB;
    float*          Hh  = out;

    wprep<<<dim3((1152 * 384 + 255) / 256), 256, 0, stream>>>(qkvw, WqT, 384, 1152);
    wprep<<<dim3((384 * 384 + 255) / 256),  256, 0, stream>>>(projw, WpT, 384, 384);
    wprep<<<dim3((384 * 1536 + 255) / 256), 256, 0, stream>>>(w1, W1T, 384, 1536);
    wprep<<<dim3((1536 * 384 + 255) / 256), 256, 0, stream>>>(w2, W2T, 1536, 384);

    // LN1 + shifted-window gather -> X1 (bf16, window-token order)
    ln_kernel<1><<<dim3(T / 4), 256, 0, stream>>>(x, n1g, n1b, X1, T);
    // QKV projection
    gemm_kernel<0><<<dim3((T / 128) * (1152 / 128)), 256, 0, stream>>>(
        X1, WqT, T, 1152, 384, nullptr, nullptr, QKV, nullptr);
    // windowed attention (reads QKV/slotB, writes O/slotA)
    attn_kernel<<<dim3((T / 49) * 12), 64, 0, stream>>>(QKV, rel, rpb, O);
    // proj + bias + un-window/un-roll + residual -> Hh (= d_out, fp32)
    gemm_kernel<1><<<dim3((T / 128) * (384 / 128)), 256, 0, stream>>>(
        O, WpT, T, 384, 384, projb, x, nullptr, Hh);
    // LN2 -> X2 (bf16, overwrites slotA)
    ln_kernel<0><<<dim3(T / 4), 256, 0, stream>>>(Hh, n2g, n2b, X2, T);
    // FFN1 + bias + GELU -> F (bf16, overwrites slotB)
    gemm_kernel<2><<<dim3((T / 128) * (1536 / 128)), 256, 0, stream>>>(
        X2, W1T, T, 1536, 384, b1, nullptr, F, nullptr);
    // FFN2 + bias + residual -> out (fp32, in-place RMW on d_out)
    gemm_kernel<3><<<dim3((T / 128) * (384 / 128)), 256, 0, stream>>>(
        F, W2T, T, 384, 1536, b2, Hh, nullptr, out);
}

// Round 11
// 955.635 us; speedup vs baseline: 1.4740x; 1.4740x over previous
//
#include <hip/hip_runtime.h>

#define DEV __device__ __forceinline__

typedef __bf16 bf16x8 __attribute__((ext_vector_type(8)));
typedef float  f32x4  __attribute__((ext_vector_type(4)));
typedef unsigned short u16x8 __attribute__((ext_vector_type(8)));

DEV float b2f(unsigned short u) {
    unsigned int t = ((unsigned int)u) << 16;
    return __uint_as_float(t);
}
DEV unsigned short f2b(float f) {
    unsigned int u = __float_as_uint(f);
    unsigned int r = (u + 0x7FFFu + ((u >> 16) & 1u)) >> 16;
    return (unsigned short)r;
}

DEV void gload_lds16(const unsigned short* g, void* l) {
    __builtin_amdgcn_global_load_lds(
        (const __attribute__((address_space(1))) void*)(const void*)g,
        (__attribute__((address_space(3))) void*)l, 16, 0, 0);
}

// dest window-row -> source/dest token index (roll by SS=3, window 7x7, 56x56, 64 win/batch)
DEV size_t win_to_tok(int row) {
    int w = row / 49, t = row - w * 49;
    int b  = w >> 6, widx = w & 63;
    int wi = widx >> 3, wj = widx & 7;
    int ti = t / 7, tj = t - ti * 7;
    int hh = wi * 7 + ti + 3; if (hh >= 56) hh -= 56;
    int ww = wj * 7 + tj + 3; if (ww >= 56) ww -= 56;
    return (size_t)b * 3136 + (size_t)hh * 56 + ww;
}

// ---------------- weight prep: fp32 [K][N] -> bf16 [N][K] ----------------
__global__ void wprep(const float* __restrict__ src, unsigned short* __restrict__ dst,
                      int K, int N) {
    int idx = blockIdx.x * 256 + threadIdx.x;
    if (idx >= K * N) return;
    int k = idx / N, n = idx - k * N;
    dst[(size_t)n * K + k] = f2b(src[idx]);
}

// ---------------- bias table: [cls 4][h 12][row 64][col 64] fp32 ----------------
// val = rpb[rel_idx[row,col], h] + shift-mask(cls,row,col); padded rows/cols -> -1e4
__global__ void btab_build(const int* __restrict__ rel_idx, const float* __restrict__ rpb,
                           float* __restrict__ tab) {
    int idx = blockIdx.x * 256 + threadIdx.x;
    if (idx >= 4 * 12 * 64 * 64) return;
    int col = idx & 63, row = (idx >> 6) & 63;
    int h = (idx >> 12) % 12, cls = idx / (12 * 4096);
    float v;
    if (row >= 49 || col >= 49) {
        v = -10000.f;
    } else {
        v = rpb[rel_idx[row * 49 + col] * 12 + h];
        int ti = row / 7, tj = row - (row / 7) * 7;
        int si = col / 7, sj = col - (col / 7) * 7;
        int lq = ((cls & 2) ? (ti < 4 ? 1 : 2) : 0) * 3 + ((cls & 1) ? (tj < 4 ? 1 : 2) : 0);
        int lk = ((cls & 2) ? (si < 4 ? 1 : 2) : 0) * 3 + ((cls & 1) ? (sj < 4 ? 1 : 2) : 0);
        if (lq != lk) v -= 100.f;
    }
    tab[idx] = v;
}

// ---------------- LayerNorm (+optional shifted-window gather), fp32 -> bf16 ----------------
template <int REMAP>
__global__ __launch_bounds__(256) void ln_kernel(const float* __restrict__ x,
                                                 const float* __restrict__ g,
                                                 const float* __restrict__ b,
                                                 unsigned short* __restrict__ out,
                                                 int rows) {
    int r = blockIdx.x * 4 + (threadIdx.x >> 6);
    int lane = threadIdx.x & 63;
    if (r >= rows) return;
    size_t src = REMAP ? win_to_tok(r) : (size_t)r;
    const float* xp = x + src * 384;
    float v[6];
    float s = 0.f;
#pragma unroll
    for (int i = 0; i < 6; ++i) { v[i] = xp[i * 64 + lane]; s += v[i]; }
#pragma unroll
    for (int off = 32; off; off >>= 1) s += __shfl_xor(s, off, 64);
    float mu = s * (1.f / 384.f);
    float q = 0.f;
#pragma unroll
    for (int i = 0; i < 6; ++i) { float d = v[i] - mu; q += d * d; }
#pragma unroll
    for (int off = 32; off; off >>= 1) q += __shfl_xor(q, off, 64);
    float inv = rsqrtf(q * (1.f / 384.f) + 1e-5f);
    unsigned short* op = out + (size_t)r * 384;
#pragma unroll
    for (int i = 0; i < 6; ++i) {
        int c = i * 64 + lane;
        op[c] = f2b((v[i] - mu) * inv * g[c] + b[c]);
    }
}

// ---------------- GEMM (R7-best): 128x128 tile, (DEPTH+1)-buffer LDS ring ----------------
// MODE 0: out bf16 = C (QKV) | 1: resid+C+bias remap fp32 (proj) | 2: gelu (FFN1) | 3: resid+C+bias (FFN2)
template <int MODE, int DEPTH, int MINW>
__global__ __launch_bounds__(256, MINW) void gemm_kernel(const unsigned short* __restrict__ A,
                                                         const unsigned short* __restrict__ Bt,
                                                         int M, int N, int K,
                                                         const float* __restrict__ bias,
                                                         const float* __restrict__ resid,
                                                         unsigned short* __restrict__ outb,
                                                         float* __restrict__ outf) {
    constexpr int NBUF = DEPTH + 1;
    __shared__ unsigned short As[NBUF][128 * 32];
    __shared__ unsigned short Bs[NBUF][128 * 32];
    const int tid = threadIdx.x;
    const int wid = tid >> 6, lane = tid & 63;
    const int ntile = N >> 7;

    int bid = blockIdx.x;
    int nwg = gridDim.x;
    int swb = ((nwg & 7) == 0) ? ((bid & 7) * (nwg >> 3) + (bid >> 3)) : bid;
    const int mt = swb / ntile, nt = swb - mt * ntile;
    const int wr = wid >> 1, wc = wid & 1;

    f32x4 acc[4][4] = {};

    const int rA   = lane >> 2;
    const int kofs = (((lane & 3) ^ ((lane >> 3) & 3)) << 3);
    const unsigned short* Abase = A  + (size_t)(mt * 128) * K;
    const unsigned short* Bbase = Bt + (size_t)(nt * 128) * K;

    auto stage = [&](int buf, int k0) {
#pragma unroll
        for (int j = 0; j < 2; ++j) {
            int c = wid * 2 + j;
            gload_lds16(Abase + (size_t)(c * 16 + rA) * K + k0 + kofs, &As[buf][c * 512]);
            gload_lds16(Bbase + (size_t)(c * 16 + rA) * K + k0 + kofs, &Bs[buf][c * 512]);
        }
    };

    const int sr  = ((lane & 15) >> 1) & 3;
    const int cbA = (((lane >> 4) ^ sr) << 3);
    const int rowA = wr * 64 + (lane & 15);
    const int rowB = wc * 64 + (lane & 15);

    const int nk = K >> 5;
    stage(0, 0);
    if (DEPTH >= 2 && nk > 1) stage(1, 32);
    if (DEPTH >= 3 && nk > 2) stage(2, 64);

    for (int t = 0; t < nk; ++t) {
        const int cur = t % NBUF;
        if (t + DEPTH < nk) {
            stage((t + DEPTH) % NBUF, (t + DEPTH) << 5);
            if constexpr (DEPTH == 1) {
                asm volatile("s_waitcnt vmcnt(4)" ::: "memory");
            } else {
                asm volatile("s_waitcnt vmcnt(12)" ::: "memory");
            }
        } else if (DEPTH >= 3 && t + 2 < nk) {
            asm volatile("s_waitcnt vmcnt(8)" ::: "memory");
        } else if (t + 1 < nk) {
            asm volatile("s_waitcnt vmcnt(4)" ::: "memory");
        } else {
            asm volatile("s_waitcnt vmcnt(0)" ::: "memory");
        }
        __builtin_amdgcn_s_barrier();

        bf16x8 a[4], b[4];
#pragma unroll
        for (int m = 0; m < 4; ++m)
            a[m] = *(const bf16x8*)&As[cur][(rowA + m * 16) * 32 + cbA];
#pragma unroll
        for (int n = 0; n < 4; ++n)
            b[n] = *(const bf16x8*)&Bs[cur][(rowB + n * 16) * 32 + cbA];
#pragma unroll
        for (int m = 0; m < 4; ++m)
#pragma unroll
            for (int n = 0; n < 4; ++n)
                acc[m][n] = __builtin_amdgcn_mfma_f32_16x16x32_bf16(a[m], b[n], acc[m][n], 0, 0, 0);

        asm volatile("s_waitcnt lgkmcnt(0)" ::: "memory");
        __builtin_amdgcn_s_barrier();
    }

    const int row0 = mt * 128 + wr * 64;
    const int col0 = nt * 128 + wc * 64;
#pragma unroll
    for (int m = 0; m < 4; ++m) {
#pragma unroll
        for (int r = 0; r < 4; ++r) {
            int row = row0 + m * 16 + ((lane >> 4) << 2) + r;
            size_t tok = 0;
            if constexpr (MODE == 1) tok = win_to_tok(row);
#pragma unroll
            for (int n = 0; n < 4; ++n) {
                int col = col0 + n * 16 + (lane & 15);
                float v = acc[m][n][r];
                if constexpr (MODE == 0) {
                    outb[(size_t)row * N + col] = f2b(v);
                } else if constexpr (MODE == 1) {
                    size_t o = tok * 384 + col;
                    outf[o] = resid[o] + v + bias[col];
                } else if constexpr (MODE == 2) {
                    float t2 = v + bias[col];
                    float y  = 0.7978845608028654f * (t2 + 0.044715f * t2 * t2 * t2);
                    float u  = __expf(-2.0f * fabsf(y));
                    float th = (1.f - u) / (1.f + u);
                    outb[(size_t)row * N + col] = f2b(0.5f * t2 * (1.f + copysignf(th, t2)));
                } else {
                    size_t o = (size_t)row * N + col;
                    outf[o] = resid[o] + v + bias[col];
                }
            }
        }
    }
}

// ---------------- MFMA attention: block = 1 window, 4 waves, 3 rounds x 4 heads ----------------
// S[64x64] = Q@K^T via 16 mfma (pad 49->64); bias from Btab; in-register softmax
// (shfl_xor row-reduce); P->LDS (swizzled); O = P@V^T via 16 mfma (V transposed at staging).
__global__ __launch_bounds__(256, 2) void attn_kernel(const unsigned short* __restrict__ QKV,
                                                      const float* __restrict__ Btab,
                                                      unsigned short* __restrict__ O) {
    __shared__ char lds[65536];
    char* Kl = lds;              // [hh][m 64][4 chunks x16B]: hh*4096 + m*64 + phys*16
    char* Vl = lds + 16384;      // [hh][d 32][8 chunks x16B]: hh*4096 + d*128 + phys*16 (V^T)
    char* Pl = lds + 32768;      // [wave][row 64][8 chunks]:  wid*8192 + row*128 + phys*16

    const int w   = blockIdx.x;
    const int tid = threadIdx.x, wid = tid >> 6, lane = tid & 63;
    const int fr  = lane & 15, kq = lane >> 4;
    const size_t base = (size_t)w * 49 * 1152;
    const int widx = w & 63, wi = widx >> 3, wj = widx & 7;
    const int cls = ((wi == 7) ? 2 : 0) | ((wj == 7) ? 1 : 0);
    const float* tb = Btab + (size_t)cls * 12 * 4096;
    constexpr float SCL = 0.17677669529663687f;

    for (int R = 0; R < 3; ++R) {
        if (R) __syncthreads();                 // prev round's K/V reads done
        {   // zero K+V regions (32 KB)
            f32x4 z = {};
#pragma unroll
            for (int j = 0; j < 8; ++j) *(f32x4*)(lds + j * 4096 + tid * 16) = z;
        }
        __syncthreads();
        {   // stage K (b128, swizzled) + V (transposed scatter) for 4 heads
            int hh = tid >> 6, h = R * 4 + hh;
#pragma unroll
            for (int it = 0; it < 4; ++it) {
                int i = (tid & 63) + it * 64;
                if (i < 196) {
                    int m = i >> 2, c = i & 3;
                    u16x8 kv = *(const u16x8*)&QKV[base + (size_t)m * 1152 + 384 + h * 32 + c * 8];
                    *(u16x8*)(Kl + hh * 4096 + m * 64 + (c ^ ((m >> 1) & 3)) * 16) = kv;
                    u16x8 vv = *(const u16x8*)&QKV[base + (size_t)m * 1152 + 768 + h * 32 + c * 8];
#pragma unroll
                    for (int j = 0; j < 8; ++j) {
                        int d = c * 8 + j;
                        *(unsigned short*)(Vl + hh * 4096 + d * 128 +
                                           (((m >> 3) ^ (d & 7)) * 16) + (m & 7) * 2) = vv[j];
                    }
                }
            }
        }
        __syncthreads();

        // ---- compute: wave wid owns head h ----
        const int h = R * 4 + wid;
        const float* tbh = tb + h * 4096;

        bf16x8 aq[4], bk[4];
#pragma unroll
        for (int mi = 0; mi < 4; ++mi) {
            int row = mi * 16 + fr; if (row > 48) row = 48;
            aq[mi] = *(const bf16x8*)&QKV[base + (size_t)row * 1152 + h * 32 + kq * 8];
        }
#pragma unroll
        for (int ni = 0; ni < 4; ++ni) {
            int rk = ni * 16 + fr;
            bk[ni] = *(const bf16x8*)(Kl + wid * 4096 + rk * 64 + ((kq ^ ((rk >> 1) & 3)) * 16));
        }
        f32x4 s[4][4] = {};
#pragma unroll
        for (int mi = 0; mi < 4; ++mi)
#pragma unroll
            for (int ni = 0; ni < 4; ++ni)
                s[mi][ni] = __builtin_amdgcn_mfma_f32_16x16x32_bf16(aq[mi], bk[ni], s[mi][ni], 0, 0, 0);

        // scale + bias + row softmax (rows: mi*16+kq*4+r; cols: ni*16+fr)
        float linv[4][4];
#pragma unroll
        for (int mi = 0; mi < 4; ++mi)
#pragma unroll
            for (int r = 0; r < 4; ++r) {
                int row = mi * 16 + kq * 4 + r;
                const float* tr = tbh + row * 64 + fr;
                float v0 = s[mi][0][r] * SCL + tr[0];
                float v1 = s[mi][1][r] * SCL + tr[16];
                float v2 = s[mi][2][r] * SCL + tr[32];
                float v3 = s[mi][3][r] * SCL + tr[48];
                float mx = fmaxf(fmaxf(v0, v1), fmaxf(v2, v3));
#pragma unroll
                for (int off = 1; off <= 8; off <<= 1) mx = fmaxf(mx, __shfl_xor(mx, off, 64));
                v0 = __expf(v0 - mx); v1 = __expf(v1 - mx);
                v2 = __expf(v2 - mx); v3 = __expf(v3 - mx);
                float sm = v0 + v1 + v2 + v3;
#pragma unroll
                for (int off = 1; off <= 8; off <<= 1) sm += __shfl_xor(sm, off, 64);
                linv[mi][r] = 1.f / sm;
                s[mi][0][r] = v0; s[mi][1][r] = v1; s[mi][2][r] = v2; s[mi][3][r] = v3;
            }

        // P -> LDS (bf16, chunk^(row&7) swizzle for 128B rows)
#pragma unroll
        for (int mi = 0; mi < 4; ++mi)
#pragma unroll
            for (int ni = 0; ni < 4; ++ni)
#pragma unroll
                for (int r = 0; r < 4; ++r) {
                    int row = mi * 16 + kq * 4 + r, col = ni * 16 + fr;
                    *(unsigned short*)(Pl + wid * 8192 + row * 128 +
                                       (((col >> 3) ^ (row & 7)) * 16) + (col & 7) * 2) =
                        f2b(s[mi][ni][r]);
                }
        asm volatile("s_waitcnt lgkmcnt(0)" ::: "memory");
        __builtin_amdgcn_sched_barrier(0);

        // O = P @ V^T
        f32x4 oacc[4][2] = {};
#pragma unroll
        for (int sl = 0; sl < 2; ++sl) {
            bf16x8 bv[2];
#pragma unroll
            for (int ni = 0; ni < 2; ++ni) {
                int d = ni * 16 + fr;
                bv[ni] = *(const bf16x8*)(Vl + wid * 4096 + d * 128 + (((sl * 4 + kq) ^ (d & 7)) * 16));
            }
#pragma unroll
            for (int mi = 0; mi < 4; ++mi) {
                int row = mi * 16 + fr;
                bf16x8 ap = *(const bf16x8*)(Pl + wid * 8192 + row * 128 + (((sl * 4 + kq) ^ (row & 7)) * 16));
#pragma unroll
                for (int ni = 0; ni < 2; ++ni)
                    oacc[mi][ni] = __builtin_amdgcn_mfma_f32_16x16x32_bf16(ap, bv[ni], oacc[mi][ni], 0, 0, 0);
            }
        }

        // O write (rows < 49 only)
#pragma unroll
        for (int mi = 0; mi < 4; ++mi)
#pragma unroll
            for (int r = 0; r < 4; ++r) {
                int row = mi * 16 + kq * 4 + r;
                if (row < 49) {
                    float li = linv[mi][r];
                    unsigned short* op = O + (size_t)(w * 49 + row) * 384 + h * 32;
                    op[fr]      = f2b(oacc[mi][0][r] * li);
                    op[16 + fr] = f2b(oacc[mi][1][r] * li);
                }
            }
    }
}

extern "C" void kernel_launch(void* const* d_in, const int* in_sizes, int n_in,
                              void* d_out, int out_size, void* d_ws, size_t ws_size,
                              hipStream_t stream) {
    const float* x     = (const float*)d_in[0];
    const int*   rel   = (const int*)  d_in[3];
    const float* rpb   = (const float*)d_in[4];
    const float* qkvw  = (const float*)d_in[5];
    const float* projw = (const float*)d_in[6];
    const float* projb = (const float*)d_in[7];
    const float* n1g   = (const float*)d_in[8];
    const float* n1b   = (const float*)d_in[9];
    const float* n2g   = (const float*)d_in[10];
    const float* n2b   = (const float*)d_in[11];
    const float* w1    = (const float*)d_in[12];
    const float* b1    = (const float*)d_in[13];
    const float* w2    = (const float*)d_in[14];
    const float* b2    = (const float*)d_in[15];
    float* out = (float*)d_out;

    const int T = in_sizes[0] / 384;   // 100352

    char* ws = (char*)d_ws;
    size_t off = 0;
    auto alloc = [&](size_t bytes) {
        char* p = ws + off;
        off += (bytes + 255) & ~(size_t)255;
        return p;
    };
    unsigned short* WqT  = (unsigned short*)alloc((size_t)1152 * 384 * 2);
    unsigned short* WpT  = (unsigned short*)alloc((size_t)384 * 384 * 2);
    unsigned short* W1T  = (unsigned short*)alloc((size_t)1536 * 384 * 2);
    unsigned short* W2T  = (unsigned short*)alloc((size_t)384 * 1536 * 2);
    float*          Btab = (float*)        alloc((size_t)4 * 12 * 4096 * 4);
    unsigned short* slotA = (unsigned short*)alloc((size_t)T * 384 * 2);   // X1 -> O -> X2
    unsigned short* slotB = (unsigned short*)alloc((size_t)T * 1536 * 2);  // QKV -> F

    unsigned short* X1  = slotA;
    unsigned short* O   = slotA;
    unsigned short* X2  = slotA;
    unsigned short* QKV = slotB;
    unsigned short* F   = slotB;
    float*          Hh  = out;

    wprep<<<dim3((1152 * 384 + 255) / 256), 256, 0, stream>>>(qkvw, WqT, 384, 1152);
    wprep<<<dim3((384 * 384 + 255) / 256),  256, 0, stream>>>(projw, WpT, 384, 384);
    wprep<<<dim3((384 * 1536 + 255) / 256), 256, 0, stream>>>(w1, W1T, 384, 1536);
    wprep<<<dim3((1536 * 384 + 255) / 256), 256, 0, stream>>>(w2, W2T, 1536, 384);
    btab_build<<<dim3((4 * 12 * 4096 + 255) / 256), 256, 0, stream>>>(rel, rpb, Btab);

    // LN1 + shifted-window gather -> X1 (bf16, window-token order)
    ln_kernel<1><<<dim3(T / 4), 256, 0, stream>>>(x, n1g, n1b, X1, T);
    // QKV projection (K=384: depth-1, reg-capped)
    gemm_kernel<0, 1, 4><<<dim3((T / 128) * (1152 / 128)), 256, 0, stream>>>(
        X1, WqT, T, 1152, 384, nullptr, nullptr, QKV, nullptr);
    // MFMA windowed attention (reads QKV/slotB, writes O/slotA)
    attn_kernel<<<dim3(T / 49), 256, 0, stream>>>(QKV, Btab, O);
    // proj + bias + un-window/un-roll + residual -> Hh (= d_out, fp32)
    gemm_kernel<1, 1, 4><<<dim3((T / 128) * (384 / 128)), 256, 0, stream>>>(
        O, WpT, T, 384, 384, projb, x, nullptr, Hh);
    // LN2 -> X2 (bf16, overwrites slotA)
    ln_kernel<0><<<dim3(T / 4), 256, 0, stream>>>(Hh, n2g, n2b, X2, T);
    // FFN1 + bias + GELU -> F (bf16, overwrites slotB)
    gemm_kernel<2, 1, 4><<<dim3((T / 128) * (1536 / 128)), 256, 0, stream>>>(
        X2, W1T, T, 1536, 384, b1, nullptr, F, nullptr);
    // FFN2 + bias + residual -> out (fp32, in-place RMW on d_out; K=1536: depth-3)
    gemm_kernel<3, 3, 2><<<dim3((T / 128) * (384 / 128)), 256, 0, stream>>>(
        F, W2T, T, 384, 1536, b2, Hh, nullptr, out);
}

// Round 12
// 948.468 us; speedup vs baseline: 1.4852x; 1.0076x over previous
//
#include <hip/hip_runtime.h>

#define DEV __device__ __forceinline__

typedef __bf16 bf16x8 __attribute__((ext_vector_type(8)));
typedef float  f32x4  __attribute__((ext_vector_type(4)));
typedef unsigned short u16x8 __attribute__((ext_vector_type(8)));
typedef unsigned short u16x4 __attribute__((ext_vector_type(4)));

DEV float b2f(unsigned short u) {
    unsigned int t = ((unsigned int)u) << 16;
    return __uint_as_float(t);
}
DEV unsigned short f2b(float f) {
    unsigned int u = __float_as_uint(f);
    unsigned int r = (u + 0x7FFFu + ((u >> 16) & 1u)) >> 16;
    return (unsigned short)r;
}

DEV void gload_lds16(const unsigned short* g, void* l) {
    __builtin_amdgcn_global_load_lds(
        (const __attribute__((address_space(1))) void*)(const void*)g,
        (__attribute__((address_space(3))) void*)l, 16, 0, 0);
}

// dest window-row -> source/dest token index (roll by SS=3, window 7x7, 56x56, 64 win/batch)
DEV size_t win_to_tok(int row) {
    int w = row / 49, t = row - w * 49;
    int b  = w >> 6, widx = w & 63;
    int wi = widx >> 3, wj = widx & 7;
    int ti = t / 7, tj = t - ti * 7;
    int hh = wi * 7 + ti + 3; if (hh >= 56) hh -= 56;
    int ww = wj * 7 + tj + 3; if (ww >= 56) ww -= 56;
    return (size_t)b * 3136 + (size_t)hh * 56 + ww;
}

// ---------------- weight prep: fp32 [K][N] -> bf16 [N][K] ----------------
__global__ void wprep(const float* __restrict__ src, unsigned short* __restrict__ dst,
                      int K, int N) {
    int idx = blockIdx.x * 256 + threadIdx.x;
    if (idx >= K * N) return;
    int k = idx / N, n = idx - k * N;
    dst[(size_t)n * K + k] = f2b(src[idx]);
}

// ---------------- bias table: [cls 4][h 12][row 64][col 64] fp32 ----------------
__global__ void btab_build(const int* __restrict__ rel_idx, const float* __restrict__ rpb,
                           float* __restrict__ tab) {
    int idx = blockIdx.x * 256 + threadIdx.x;
    if (idx >= 4 * 12 * 64 * 64) return;
    int col = idx & 63, row = (idx >> 6) & 63;
    int h = (idx >> 12) % 12, cls = idx / (12 * 4096);
    float v;
    if (row >= 49 || col >= 49) {
        v = -10000.f;
    } else {
        v = rpb[rel_idx[row * 49 + col] * 12 + h];
        int ti = row / 7, tj = row - (row / 7) * 7;
        int si = col / 7, sj = col - (col / 7) * 7;
        int lq = ((cls & 2) ? (ti < 4 ? 1 : 2) : 0) * 3 + ((cls & 1) ? (tj < 4 ? 1 : 2) : 0);
        int lk = ((cls & 2) ? (si < 4 ? 1 : 2) : 0) * 3 + ((cls & 1) ? (sj < 4 ? 1 : 2) : 0);
        if (lq != lk) v -= 100.f;
    }
    tab[idx] = v;
}

// ---------------- LayerNorm (+optional shifted-window gather), fp32 -> bf16 ----------------
template <int REMAP>
__global__ __launch_bounds__(256) void ln_kernel(const float* __restrict__ x,
                                                 const float* __restrict__ g,
                                                 const float* __restrict__ b,
                                                 unsigned short* __restrict__ out,
                                                 int rows) {
    int r = blockIdx.x * 4 + (threadIdx.x >> 6);
    int lane = threadIdx.x & 63;
    if (r >= rows) return;
    size_t src = REMAP ? win_to_tok(r) : (size_t)r;
    const float* xp = x + src * 384;
    float v[6];
    float s = 0.f;
#pragma unroll
    for (int i = 0; i < 6; ++i) { v[i] = xp[i * 64 + lane]; s += v[i]; }
#pragma unroll
    for (int off = 32; off; off >>= 1) s += __shfl_xor(s, off, 64);
    float mu = s * (1.f / 384.f);
    float q = 0.f;
#pragma unroll
    for (int i = 0; i < 6; ++i) { float d = v[i] - mu; q += d * d; }
#pragma unroll
    for (int off = 32; off; off >>= 1) q += __shfl_xor(q, off, 64);
    float inv = rsqrtf(q * (1.f / 384.f) + 1e-5f);
    unsigned short* op = out + (size_t)r * 384;
#pragma unroll
    for (int i = 0; i < 6; ++i) {
        int c = i * 64 + lane;
        op[c] = f2b((v[i] - mu) * inv * g[c] + b[c]);
    }
}

// ---------------- GEMM (R7 schedule + swapped-operand vectorized epilogue) ----------------
// acc[m][n] = mfma(b[n], a[m], acc): lane&15 = C-row (within 16), (lane>>4)*4+r = C-col.
// -> each lane stores 4 consecutive cols per fragment: u16x4 / f32x4 stores.
// MODE 0: out bf16 = C (QKV) | 1: resid+C+bias remap fp32 (proj) | 2: gelu (FFN1) | 3: resid+C+bias (FFN2)
template <int MODE, int DEPTH, int MINW>
__global__ __launch_bounds__(256, MINW) void gemm_kernel(const unsigned short* __restrict__ A,
                                                         const unsigned short* __restrict__ Bt,
                                                         int M, int N, int K,
                                                         const float* __restrict__ bias,
                                                         const float* __restrict__ resid,
                                                         unsigned short* __restrict__ outb,
                                                         float* __restrict__ outf) {
    constexpr int NBUF = DEPTH + 1;
    __shared__ unsigned short As[NBUF][128 * 32];
    __shared__ unsigned short Bs[NBUF][128 * 32];
    const int tid = threadIdx.x;
    const int wid = tid >> 6, lane = tid & 63;
    const int ntile = N >> 7;

    int bid = blockIdx.x;
    int nwg = gridDim.x;
    int swb = ((nwg & 7) == 0) ? ((bid & 7) * (nwg >> 3) + (bid >> 3)) : bid;
    const int mt = swb / ntile, nt = swb - mt * ntile;
    const int wr = wid >> 1, wc = wid & 1;

    f32x4 acc[4][4] = {};

    const int rA   = lane >> 2;
    const int kofs = (((lane & 3) ^ ((lane >> 3) & 3)) << 3);
    const unsigned short* Abase = A  + (size_t)(mt * 128) * K;
    const unsigned short* Bbase = Bt + (size_t)(nt * 128) * K;

    auto stage = [&](int buf, int k0) {
#pragma unroll
        for (int j = 0; j < 2; ++j) {
            int c = wid * 2 + j;
            gload_lds16(Abase + (size_t)(c * 16 + rA) * K + k0 + kofs, &As[buf][c * 512]);
            gload_lds16(Bbase + (size_t)(c * 16 + rA) * K + k0 + kofs, &Bs[buf][c * 512]);
        }
    };

    const int sr  = ((lane & 15) >> 1) & 3;
    const int cbA = (((lane >> 4) ^ sr) << 3);
    const int rowA = wr * 64 + (lane & 15);
    const int rowB = wc * 64 + (lane & 15);

    const int nk = K >> 5;
    stage(0, 0);
    if (DEPTH >= 2 && nk > 1) stage(1, 32);
    if (DEPTH >= 3 && nk > 2) stage(2, 64);

    for (int t = 0; t < nk; ++t) {
        const int cur = t % NBUF;
        if (t + DEPTH < nk) {
            stage((t + DEPTH) % NBUF, (t + DEPTH) << 5);
            if constexpr (DEPTH == 1) {
                asm volatile("s_waitcnt vmcnt(4)" ::: "memory");
            } else {
                asm volatile("s_waitcnt vmcnt(12)" ::: "memory");
            }
        } else if (DEPTH >= 3 && t + 2 < nk) {
            asm volatile("s_waitcnt vmcnt(8)" ::: "memory");
        } else if (t + 1 < nk) {
            asm volatile("s_waitcnt vmcnt(4)" ::: "memory");
        } else {
            asm volatile("s_waitcnt vmcnt(0)" ::: "memory");
        }
        __builtin_amdgcn_s_barrier();

        bf16x8 a[4], b[4];
#pragma unroll
        for (int m = 0; m < 4; ++m)
            a[m] = *(const bf16x8*)&As[cur][(rowA + m * 16) * 32 + cbA];
#pragma unroll
        for (int n = 0; n < 4; ++n)
            b[n] = *(const bf16x8*)&Bs[cur][(rowB + n * 16) * 32 + cbA];
        // swapped operands: lane&15 indexes A-rows (C rows), regs index B-rows (C cols)
#pragma unroll
        for (int m = 0; m < 4; ++m)
#pragma unroll
            for (int n = 0; n < 4; ++n)
                acc[m][n] = __builtin_amdgcn_mfma_f32_16x16x32_bf16(b[n], a[m], acc[m][n], 0, 0, 0);

        asm volatile("s_waitcnt lgkmcnt(0)" ::: "memory");
        __builtin_amdgcn_s_barrier();
    }

    const int row0 = mt * 128 + wr * 64;
    const int col0 = nt * 128 + wc * 64;
    const int rl = lane & 15;
    const int cq = (lane >> 4) << 2;   // col quarter: 0,4,8,12
#pragma unroll
    for (int m = 0; m < 4; ++m) {
        int row = row0 + m * 16 + rl;
        size_t tok = 0;
        if constexpr (MODE == 1) tok = win_to_tok(row);
#pragma unroll
        for (int n = 0; n < 4; ++n) {
            int col = col0 + n * 16 + cq;
            f32x4 v = acc[m][n];   // v[r] = C[row][col+r]
            if constexpr (MODE == 0) {
                u16x4 pk;
#pragma unroll
                for (int r = 0; r < 4; ++r) pk[r] = f2b(v[r]);
                *(u16x4*)&outb[(size_t)row * N + col] = pk;
            } else if constexpr (MODE == 1) {
                size_t o = tok * 384 + col;
                f32x4 rv = *(const f32x4*)&resid[o];
                f32x4 bb = *(const f32x4*)&bias[col];
                f32x4 ov = rv + v + bb;
                *(f32x4*)&outf[o] = ov;
            } else if constexpr (MODE == 2) {
                f32x4 bb = *(const f32x4*)&bias[col];
                u16x4 pk;
#pragma unroll
                for (int r = 0; r < 4; ++r) {
                    float t2 = v[r] + bb[r];
                    float y  = 0.7978845608028654f * (t2 + 0.044715f * t2 * t2 * t2);
                    float u  = __expf(-2.0f * fabsf(y));
                    float th = (1.f - u) / (1.f + u);
                    pk[r] = f2b(0.5f * t2 * (1.f + copysignf(th, t2)));
                }
                *(u16x4*)&outb[(size_t)row * N + col] = pk;
            } else {
                size_t o = (size_t)row * N + col;
                f32x4 rv = *(const f32x4*)&resid[o];
                f32x4 bb = *(const f32x4*)&bias[col];
                f32x4 ov = rv + v + bb;
                *(f32x4*)&outf[o] = ov;
            }
        }
    }
}

// ---------------- MFMA attention (swapped operands: lane-local softmax rows) ----------------
// Block = 1 window, 4 waves, 3 rounds x 4 heads. s = mfma(K,Q): lane&15 = q-row,
// regs = k-cols -> softmax row-reduce needs only shfl_xor(16,32) over kq lanes.
__global__ __launch_bounds__(256, 2) void attn_kernel(const unsigned short* __restrict__ QKV,
                                                      const float* __restrict__ Btab,
                                                      unsigned short* __restrict__ O) {
    __shared__ char lds[65536];
    char* Kl = lds;              // [hh][m 64][4 chunks x16B]: hh*4096 + m*64 + phys*16
    char* Vl = lds + 16384;      // [hh][d 32][8 chunks x16B]: hh*4096 + d*128 + phys*16 (V^T)
    char* Pl = lds + 32768;      // [wave][row 64][8 chunks]:  wid*8192 + row*128 + phys*16

    const int w   = blockIdx.x;
    const int tid = threadIdx.x, wid = tid >> 6, lane = tid & 63;
    const int fr  = lane & 15, kq = lane >> 4;
    const size_t base = (size_t)w * 49 * 1152;
    const int widx = w & 63, wi = widx >> 3, wj = widx & 7;
    const int cls = ((wi == 7) ? 2 : 0) | ((wj == 7) ? 1 : 0);
    const float* tb = Btab + (size_t)cls * 12 * 4096;
    constexpr float SCL = 0.17677669529663687f;

    for (int R = 0; R < 3; ++R) {
        if (R) __syncthreads();
        {   // zero K+V regions (32 KB)
            f32x4 z = {};
#pragma unroll
            for (int j = 0; j < 8; ++j) *(f32x4*)(lds + j * 4096 + tid * 16) = z;
        }
        __syncthreads();
        {   // stage K (b128, swizzled) + V (transposed scatter) for 4 heads
            int hh = tid >> 6, h = R * 4 + hh;
#pragma unroll
            for (int it = 0; it < 4; ++it) {
                int i = (tid & 63) + it * 64;
                if (i < 196) {
                    int m = i >> 2, c = i & 3;
                    u16x8 kv = *(const u16x8*)&QKV[base + (size_t)m * 1152 + 384 + h * 32 + c * 8];
                    *(u16x8*)(Kl + hh * 4096 + m * 64 + (c ^ ((m >> 1) & 3)) * 16) = kv;
                    u16x8 vv = *(const u16x8*)&QKV[base + (size_t)m * 1152 + 768 + h * 32 + c * 8];
#pragma unroll
                    for (int j = 0; j < 8; ++j) {
                        int d = c * 8 + j;
                        *(unsigned short*)(Vl + hh * 4096 + d * 128 +
                                           (((m >> 3) ^ (d & 7)) * 16) + (m & 7) * 2) = vv[j];
                    }
                }
            }
        }
        __syncthreads();

        const int h = R * 4 + wid;
        const float* tbh = tb + h * 4096;

        bf16x8 aq[4], bk[4];
#pragma unroll
        for (int mi = 0; mi < 4; ++mi) {
            int row = mi * 16 + fr; if (row > 48) row = 48;
            aq[mi] = *(const bf16x8*)&QKV[base + (size_t)row * 1152 + h * 32 + kq * 8];
        }
#pragma unroll
        for (int ni = 0; ni < 4; ++ni) {
            int rk = ni * 16 + fr;
            bk[ni] = *(const bf16x8*)(Kl + wid * 4096 + rk * 64 + ((kq ^ ((rk >> 1) & 3)) * 16));
        }
        // swapped: lane&15 = q-row, reg = k-col
        f32x4 s[4][4] = {};
#pragma unroll
        for (int mi = 0; mi < 4; ++mi)
#pragma unroll
            for (int ni = 0; ni < 4; ++ni)
                s[mi][ni] = __builtin_amdgcn_mfma_f32_16x16x32_bf16(bk[ni], aq[mi], s[mi][ni], 0, 0, 0);

        // scale + bias + softmax (row = mi*16+fr lane-local; cols = ni*16 + kq*4 + r)
        float linv_[4];
#pragma unroll
        for (int mi = 0; mi < 4; ++mi) {
            int row = mi * 16 + fr;
            const float* tr = tbh + row * 64 + kq * 4;
            f32x4 sv[4];
            float mx = -1e30f;
#pragma unroll
            for (int ni = 0; ni < 4; ++ni) {
                f32x4 bb = *(const f32x4*)&tr[ni * 16];
                sv[ni] = s[mi][ni] * SCL + bb;
                mx = fmaxf(mx, fmaxf(fmaxf(sv[ni][0], sv[ni][1]), fmaxf(sv[ni][2], sv[ni][3])));
            }
            mx = fmaxf(mx, __shfl_xor(mx, 16, 64));
            mx = fmaxf(mx, __shfl_xor(mx, 32, 64));
            float sm = 0.f;
#pragma unroll
            for (int ni = 0; ni < 4; ++ni)
#pragma unroll
                for (int r = 0; r < 4; ++r) { sv[ni][r] = __expf(sv[ni][r] - mx); sm += sv[ni][r]; }
            sm += __shfl_xor(sm, 16, 64);
            sm += __shfl_xor(sm, 32, 64);
            linv_[mi] = 1.f / sm;
            // P store: 4 consecutive cols -> u16x4 (swizzle chunk = col>>3 ^ (row&7))
#pragma unroll
            for (int ni = 0; ni < 4; ++ni) {
                int colb = ni * 16 + kq * 4;
                int phys = (colb >> 3) ^ (row & 7);
                u16x4 pk;
#pragma unroll
                for (int r = 0; r < 4; ++r) pk[r] = f2b(sv[ni][r]);
                *(u16x4*)(Pl + wid * 8192 + row * 128 + phys * 16 + (colb & 7) * 2) = pk;
            }
        }
        asm volatile("s_waitcnt lgkmcnt(0)" ::: "memory");
        __builtin_amdgcn_sched_barrier(0);

        // O = P @ V^T (swapped: lane&15 = q-row, reg = d-col)
        f32x4 oacc[4][2] = {};
#pragma unroll
        for (int sl = 0; sl < 2; ++sl) {
            bf16x8 bv[2];
#pragma unroll
            for (int ni = 0; ni < 2; ++ni) {
                int d = ni * 16 + fr;
                bv[ni] = *(const bf16x8*)(Vl + wid * 4096 + d * 128 + (((sl * 4 + kq) ^ (d & 7)) * 16));
            }
#pragma unroll
            for (int mi = 0; mi < 4; ++mi) {
                int row = mi * 16 + fr;
                bf16x8 ap = *(const bf16x8*)(Pl + wid * 8192 + row * 128 + (((sl * 4 + kq) ^ (row & 7)) * 16));
#pragma unroll
                for (int ni = 0; ni < 2; ++ni)
                    oacc[mi][ni] = __builtin_amdgcn_mfma_f32_16x16x32_bf16(bv[ni], ap, oacc[mi][ni], 0, 0, 0);
            }
        }

        // O write: row = mi*16+fr (<49); cols ni*16 + kq*4 + {0..3} scaled by linv
#pragma unroll
        for (int mi = 0; mi < 4; ++mi) {
            int row = mi * 16 + fr;
            if (row < 49) {
                float li = linv_[mi];
                unsigned short* op = O + (size_t)(w * 49 + row) * 384 + h * 32 + kq * 4;
#pragma unroll
                for (int ni = 0; ni < 2; ++ni) {
                    u16x4 pk;
#pragma unroll
                    for (int r = 0; r < 4; ++r) pk[r] = f2b(oacc[mi][ni][r] * li);
                    *(u16x4*)&op[ni * 16] = pk;
                }
            }
        }
    }
}

extern "C" void kernel_launch(void* const* d_in, const int* in_sizes, int n_in,
                              void* d_out, int out_size, void* d_ws, size_t ws_size,
                              hipStream_t stream) {
    const float* x     = (const float*)d_in[0];
    const int*   rel   = (const int*)  d_in[3];
    const float* rpb   = (const float*)d_in[4];
    const float* qkvw  = (const float*)d_in[5];
    const float* projw = (const float*)d_in[6];
    const float* projb = (const float*)d_in[7];
    const float* n1g   = (const float*)d_in[8];
    const float* n1b   = (const float*)d_in[9];
    const float* n2g   = (const float*)d_in[10];
    const float* n2b   = (const float*)d_in[11];
    const float* w1    = (const float*)d_in[12];
    const float* b1    = (const float*)d_in[13];
    const float* w2    = (const float*)d_in[14];
    const float* b2    = (const float*)d_in[15];
    float* out = (float*)d_out;

    const int T = in_sizes[0] / 384;   // 100352

    char* ws = (char*)d_ws;
    size_t off = 0;
    auto alloc = [&](size_t bytes) {
        char* p = ws + off;
        off += (bytes + 255) & ~(size_t)255;
        return p;
    };
    unsigned short* WqT  = (unsigned short*)alloc((size_t)1152 * 384 * 2);
    unsigned short* WpT  = (unsigned short*)alloc((size_t)384 * 384 * 2);
    unsigned short* W1T  = (unsigned short*)alloc((size_t)1536 * 384 * 2);
    unsigned short* W2T  = (unsigned short*)alloc((size_t)384 * 1536 * 2);
    float*          Btab = (float*)        alloc((size_t)4 * 12 * 4096 * 4);
    unsigned short* slotA = (unsigned short*)alloc((size_t)T * 384 * 2);   // X1 -> O -> X2
    unsigned short* slotB = (unsigned short*)alloc((size_t)T * 1536 * 2);  // QKV -> F

    unsigned short* X1  = slotA;
    unsigned short* O   = slotA;
    unsigned short* X2  = slotA;
    unsigned short* QKV = slotB;
    unsigned short* F   = slotB;
    float*          Hh  = out;

    wprep<<<dim3((1152 * 384 + 255) / 256), 256, 0, stream>>>(qkvw, WqT, 384, 1152);
    wprep<<<dim3((384 * 384 + 255) / 256),  256, 0, stream>>>(projw, WpT, 384, 384);
    wprep<<<dim3((384 * 1536 + 255) / 256), 256, 0, stream>>>(w1, W1T, 384, 1536);
    wprep<<<dim3((1536 * 384 + 255) / 256), 256, 0, stream>>>(w2, W2T, 1536, 384);
    btab_build<<<dim3((4 * 12 * 4096 + 255) / 256), 256, 0, stream>>>(rel, rpb, Btab);

    // LN1 + shifted-window gather -> X1 (bf16, window-token order)
    ln_kernel<1><<<dim3(T / 4), 256, 0, stream>>>(x, n1g, n1b, X1, T);
    // QKV projection (K=384: depth-1, reg-capped)
    gemm_kernel<0, 1, 4><<<dim3((T / 128) * (1152 / 128)), 256, 0, stream>>>(
        X1, WqT, T, 1152, 384, nullptr, nullptr, QKV, nullptr);
    // MFMA windowed attention
    attn_kernel<<<dim3(T / 49), 256, 0, stream>>>(QKV, Btab, O);
    // proj + bias + un-window/un-roll + residual -> Hh (= d_out, fp32)
    gemm_kernel<1, 1, 4><<<dim3((T / 128) * (384 / 128)), 256, 0, stream>>>(
        O, WpT, T, 384, 384, projb, x, nullptr, Hh);
    // LN2 -> X2 (bf16, overwrites slotA)
    ln_kernel<0><<<dim3(T / 4), 256, 0, stream>>>(Hh, n2g, n2b, X2, T);
    // FFN1 + bias + GELU -> F (bf16, overwrites slotB)
    gemm_kernel<2, 1, 4><<<dim3((T / 128) * (1536 / 128)), 256, 0, stream>>>(
        X2, W1T, T, 1536, 384, b1, nullptr, F, nullptr);
    // FFN2 + bias + residual -> out (fp32, in-place RMW on d_out; K=1536: depth-3)
    gemm_kernel<3, 3, 2><<<dim3((T / 128) * (384 / 128)), 256, 0, stream>>>(
        F, W2T, T, 384, 1536, b2, Hh, nullptr, out);
}